// Round 2
// 237.981 us; speedup vs baseline: 1.0034x; 1.0034x over previous
//
#include <hip/hip_runtime.h>

typedef float f32x4 __attribute__((ext_vector_type(4)));

#define B_  8
#define C_  64
#define H_  256
#define W_  256
#define REP_ 512

__global__ __launch_bounds__(256) void compute_kern_k(const float* __restrict__ rep,
                                                      const float* __restrict__ wkey,
                                                      float* __restrict__ kern) {
    int wave = blockIdx.x * 4 + (threadIdx.x >> 6);   // 0..4607
    int lane = threadIdx.x & 63;
    int b = wave / 576;
    int o = wave - b * 576;
    const float* wrow = wkey + (size_t)o * REP_;
    const float* rrow = rep  + (size_t)b * REP_;
    float acc = 0.f;
#pragma unroll
    for (int i = 0; i < REP_ / 64; ++i) {
        int r = lane + i * 64;
        acc += rrow[r] * wrow[r];
    }
#pragma unroll
    for (int off = 32; off > 0; off >>= 1)
        acc += __shfl_xor(acc, off, 64);
    if (lane == 0) {
        float v = acc;
        kern[wave] = v > 0.f ? v : 0.1f * v;   // LeakyReLU(0.1)
    }
}

// Rolling-window pipelined depthwise 3x3:
//  - each wave owns 16 output rows (full 256-wide row per float4-load);
//  - depth-6 register ring of rows keeps ~4 KB of loads continuously in
//    flight per wave (steady-state MLP) instead of one 10 KB burst/wave;
//  - ring slots statically indexed via full unroll (no scratch);
//  - non-temporal stores: output is never re-read, keep input in L2/L3.
#define RING 6
#define RPW  16   // output rows per wave

__global__ __launch_bounds__(256) void dwconv3x3_pipe(const float* __restrict__ x,
                                                      const float* __restrict__ kern,
                                                      float* __restrict__ out) {
    int plane   = blockIdx.x >> 2;          // b*64 + c   (4 blocks per plane)
    int quarter = blockIdx.x & 3;           // 64-row band of the plane
    int wv   = threadIdx.x >> 6;            // wave: 16-row sub-band
    int lane = threadIdx.x & 63;
    int r0 = quarter * 64 + wv * RPW;       // first output row
    int c4 = lane << 2;                     // this lane's 4 columns

    const float* pin  = x   + (size_t)plane * (H_ * W_);
    float*       pout = out + (size_t)plane * (H_ * W_);
    const float* kp   = kern + plane * 9;
    float k[9];
#pragma unroll
    for (int i = 0; i < 9; ++i) k[i] = kp[i];   // block-uniform

    f32x4 raw[RING];
    float lft[RING], rgt[RING];

    // issue load of local row i (t = r0-1+i) into ring slot i%RING
    auto issue = [&](int i) {
        int t = r0 - 1 + i;
        int rr = (t < 0) ? -t : ((t >= H_) ? (2 * H_ - 2 - t) : t);  // reflect
        raw[i % RING] = *(const f32x4*)(pin + (size_t)rr * W_ + c4);
    };
    // halo-expand row i (consumes the arrived load; registers only)
    auto prep = [&](int i) {
        int s = i % RING;
        float lv = __shfl(raw[s][3], lane - 1, 64);
        lft[s] = (lane == 0) ? raw[s][1] : lv;            // col -1 -> col 1
        float rv = __shfl(raw[s][0], lane + 1, 64);
        rgt[s] = (lane == 63) ? raw[s][2] : rv;           // col 256 -> col 254
    };
    // element accessor: local row i, window col t in [0,6)
    auto e = [&](int i, int t) -> float {
        int s = i % RING;
        if (t == 0) return lft[s];
        if (t == 5) return rgt[s];
        return raw[s][t - 1];
    };

    // prologue: fill the ring (6 loads in flight), prepare first two rows
#pragma unroll
    for (int i = 0; i < RING; ++i) issue(i);
    prep(0);
    prep(1);

    // steady state: prepare row j+2, compute+store row j, refill ring slot
#pragma unroll
    for (int j = 0; j < RPW; ++j) {
        prep(j + 2);
        f32x4 o4;
#pragma unroll
        for (int t = 0; t < 4; ++t) {
            o4[t] = k[0] * e(j, t)     + k[1] * e(j, t + 1)     + k[2] * e(j, t + 2)
                  + k[3] * e(j + 1, t) + k[4] * e(j + 1, t + 1) + k[5] * e(j + 1, t + 2)
                  + k[6] * e(j + 2, t) + k[7] * e(j + 2, t + 1) + k[8] * e(j + 2, t + 2);
        }
        __builtin_nontemporal_store(o4, (f32x4*)(pout + (size_t)(r0 + j) * W_ + c4));
        if (j + RING < RPW + 2) issue(j + RING);   // rows 6..17
    }
}

extern "C" void kernel_launch(void* const* d_in, const int* in_sizes, int n_in,
                              void* d_out, int out_size, void* d_ws, size_t ws_size,
                              hipStream_t stream) {
    const float* x    = (const float*)d_in[0];   // [8,64,256,256]
    const float* rep  = (const float*)d_in[1];   // [8,512]
    const float* wkey = (const float*)d_in[2];   // [576,512]
    float* out  = (float*)d_out;                 // [8,64,256,256]
    float* kern = (float*)d_ws;                  // 4608 floats scratch

    compute_kern_k<<<1152, 256, 0, stream>>>(rep, wkey, kern);
    // 512 planes * 4 quarter-bands, 256 threads (4 waves x 16-row sub-bands)
    dwconv3x3_pipe<<<2048, 256, 0, stream>>>(x, kern, out);
}

// Round 3
// 237.506 us; speedup vs baseline: 1.0054x; 1.0020x over previous
//
#include <hip/hip_runtime.h>

typedef float f32x4 __attribute__((ext_vector_type(4)));

#define B_  8
#define C_  64
#define H_  256
#define W_  256
#define REP_ 512

// Fused: each block computes its plane's 9 dynamic-kernel taps (Linear +
// LeakyReLU) into LDS, then does the depthwise 3x3 over its 64-row band.
// No workspace, no separate kernel launch, no serial dependency.
//
// NOTE: conv schedule kept from the "pipe" variant — rounds 0-2 proved the
// conv dispatch time is schedule-insensitive (strip8 and ring-6 both 80.8us,
// compiler collapses source-level pipelining; VGPR 28-32 either way).

#define RING 6
#define RPW  16   // output rows per wave

__global__ __launch_bounds__(256) void dwconv3x3_fused(const float* __restrict__ x,
                                                       const float* __restrict__ rep,
                                                       const float* __restrict__ wkey,
                                                       float* __restrict__ out) {
    int plane   = blockIdx.x >> 2;          // b*64 + c   (4 blocks per plane)
    int quarter = blockIdx.x & 3;           // 64-row band of the plane
    int wv   = threadIdx.x >> 6;            // wave id within block
    int lane = threadIdx.x & 63;
    int b = plane >> 6;
    int c = plane & 63;

    // ---- phase 0: this plane's 9 kernel taps (redundant per quarter-block,
    // but wkey is 1.18 MB = L2-resident; ~18 KB read per block) ----
    __shared__ float kk[9];
    const float* rrow = rep + (size_t)b * REP_;
    for (int i = wv; i < 9; i += 4) {                      // waves split the 9 rows
        const float* wrow = wkey + (size_t)(c * 9 + i) * REP_;
        float acc = 0.f;
#pragma unroll
        for (int t = 0; t < REP_ / 64; ++t)
            acc += rrow[lane + t * 64] * wrow[lane + t * 64];
#pragma unroll
        for (int off = 32; off > 0; off >>= 1)
            acc += __shfl_xor(acc, off, 64);
        if (lane == 0)
            kk[i] = acc > 0.f ? acc : 0.1f * acc;          // LeakyReLU(0.1)
    }
    __syncthreads();

    float k[9];
#pragma unroll
    for (int i = 0; i < 9; ++i) k[i] = kk[i];              // block-uniform

    // ---- conv over this wave's 16-row band ----
    int r0 = quarter * 64 + wv * RPW;       // first output row
    int c4 = lane << 2;                     // this lane's 4 columns

    const float* pin  = x   + (size_t)plane * (H_ * W_);
    float*       pout = out + (size_t)plane * (H_ * W_);

    f32x4 raw[RING];
    float lft[RING], rgt[RING];

    auto issue = [&](int i) {
        int t = r0 - 1 + i;
        int rr = (t < 0) ? -t : ((t >= H_) ? (2 * H_ - 2 - t) : t);  // reflect
        raw[i % RING] = *(const f32x4*)(pin + (size_t)rr * W_ + c4);
    };
    auto prep = [&](int i) {
        int s = i % RING;
        float lv = __shfl(raw[s][3], lane - 1, 64);
        lft[s] = (lane == 0) ? raw[s][1] : lv;            // col -1 -> col 1
        float rv = __shfl(raw[s][0], lane + 1, 64);
        rgt[s] = (lane == 63) ? raw[s][2] : rv;           // col 256 -> col 254
    };
    auto e = [&](int i, int t) -> float {
        int s = i % RING;
        if (t == 0) return lft[s];
        if (t == 5) return rgt[s];
        return raw[s][t - 1];
    };

#pragma unroll
    for (int i = 0; i < RING; ++i) issue(i);
    prep(0);
    prep(1);

#pragma unroll
    for (int j = 0; j < RPW; ++j) {
        prep(j + 2);
        f32x4 o4;
#pragma unroll
        for (int t = 0; t < 4; ++t) {
            o4[t] = k[0] * e(j, t)     + k[1] * e(j, t + 1)     + k[2] * e(j, t + 2)
                  + k[3] * e(j + 1, t) + k[4] * e(j + 1, t + 1) + k[5] * e(j + 1, t + 2)
                  + k[6] * e(j + 2, t) + k[7] * e(j + 2, t + 1) + k[8] * e(j + 2, t + 2);
        }
        __builtin_nontemporal_store(o4, (f32x4*)(pout + (size_t)(r0 + j) * W_ + c4));
        if (j + RING < RPW + 2) issue(j + RING);   // rows 6..17
    }
}

extern "C" void kernel_launch(void* const* d_in, const int* in_sizes, int n_in,
                              void* d_out, int out_size, void* d_ws, size_t ws_size,
                              hipStream_t stream) {
    const float* x    = (const float*)d_in[0];   // [8,64,256,256]
    const float* rep  = (const float*)d_in[1];   // [8,512]
    const float* wkey = (const float*)d_in[2];   // [576,512]
    float* out  = (float*)d_out;                 // [8,64,256,256]
    (void)d_ws; (void)ws_size;                   // workspace deliberately unused

    // 512 planes * 4 quarter-bands, 256 threads (4 waves x 16-row sub-bands)
    dwconv3x3_fused<<<2048, 256, 0, stream>>>(x, rep, wkey, out);
}